// Round 4
// baseline (1055.602 us; speedup 1.0000x reference)
//
#include <hip/hip_runtime.h>
#include <hip/hip_bf16.h>

// TAGConv x2 GNN on MI355X. v4:
//  - all node features fp16 (halves gather + GEMM-A traffic)
//  - linear-prop: g = dis*relu(h) (relu only at layer input); h = dis*sum g + deg*EPS
//  - grid-stride prop, 4 outstanding gathers/wave
//  - GEMM: f16 MFMA, A fp16, B split (hi + lo*1024 fp16 planes, 2 MFMAs/step)
//  - concat-K: 7 hop features as [N][896], one GEMM per TAGConv layer

#define EPS_MSG 1e-7f
#define BNSCALE 0.9999950000374997f  // 1/sqrt(1+1e-5)
#define LO_INV 0.0009765625f         // 2^-10

typedef _Float16 half_t;
typedef _Float16 f16x8 __attribute__((ext_vector_type(8)));
typedef float f32x4 __attribute__((ext_vector_type(4)));

// ---------------- CSR build ----------------

__global__ void zero_i32(int* __restrict__ p, int n) {
    int i = blockIdx.x * blockDim.x + threadIdx.x;
    if (i < n) p[i] = 0;
}

__global__ void count_deg(const int* __restrict__ col, int* __restrict__ deg, int E) {
    int e = blockIdx.x * blockDim.x + threadIdx.x;
    if (e < E) atomicAdd(&deg[col[e]], 1);
}

__global__ void compute_dis(const int* __restrict__ deg, float* __restrict__ dis, int N) {
    int v = blockIdx.x * blockDim.x + threadIdx.x;
    if (v < N) dis[v] = (deg[v] > 0) ? rsqrtf((float)deg[v]) : 0.f;
}

__global__ void scan_blk(const int* __restrict__ deg, int* __restrict__ off,
                         int* __restrict__ bsum, int N) {
    __shared__ int s[1024];
    int i = blockIdx.x * 1024 + threadIdx.x;
    s[threadIdx.x] = (i < N) ? deg[i] : 0;
    __syncthreads();
    for (int ofs = 1; ofs < 1024; ofs <<= 1) {
        int t = (threadIdx.x >= (unsigned)ofs) ? s[threadIdx.x - ofs] : 0;
        __syncthreads();
        s[threadIdx.x] += t;
        __syncthreads();
    }
    if (i < N) off[i + 1] = s[threadIdx.x];
    if (threadIdx.x == 0) bsum[blockIdx.x] = s[1023];
}

__global__ void scan_top(int* __restrict__ bsum, int nb) {
    if (threadIdx.x == 0 && blockIdx.x == 0) {
        int a = 0;
        for (int b = 0; b < nb; ++b) {
            int t = bsum[b];
            bsum[b] = a;
            a += t;
        }
    }
}

__global__ void scan_add(int* __restrict__ off, const int* __restrict__ bsum, int N) {
    int i = blockIdx.x * 1024 + threadIdx.x;
    if (i < N) off[i + 1] += bsum[blockIdx.x];
    if (i == 0) off[0] = 0;
}

__global__ void fill_edges(const int* __restrict__ row, const int* __restrict__ col,
                           const int* __restrict__ off, int* __restrict__ cur,
                           int* __restrict__ esrc, int E) {
    int e = blockIdx.x * blockDim.x + threadIdx.x;
    if (e >= E) return;
    int c = col[e];
    int pos = off[c] + atomicAdd(&cur[c], 1);
    esrc[pos] = row[e];
}

// ---------------- conversions ----------------

// h0 = fp16(x) (stride hs), g0 = fp16(dis*relu(x))
__global__ void conv_xg(const float* __restrict__ x, half_t* __restrict__ h, int hs,
                        half_t* __restrict__ g, const float* __restrict__ dis, int total) {
    int i = blockIdx.x * blockDim.x + threadIdx.x;
    if (i >= total) return;
    int v = i >> 7, c = i & 127;
    float xv = x[i];
    h[(size_t)v * hs + c] = (half_t)xv;
    g[i] = (half_t)(dis[v] * fmaxf(xv, 0.f));
}

// B^T planes: oh[n][km*K+k] = fp16(w), ol = fp16((w - fp16(w)) * 1024)
__global__ void conv_wt2(const float* __restrict__ in, half_t* __restrict__ oh,
                         half_t* __restrict__ ol, int nmats, int K, int Nn) {
    int total = nmats * K * Nn;
    int i = blockIdx.x * blockDim.x + threadIdx.x;
    if (i >= total) return;
    int KT = nmats * K;
    int n = i / KT;
    int rem = i - n * KT;
    int km = rem / K, k = rem - km * K;
    float w = in[(size_t)km * K * Nn + (size_t)k * Nn + n];
    half_t h = (half_t)w;
    oh[i] = h;
    ol[i] = (half_t)((w - (float)h) * 1024.f);
}

// ---------------- propagation: h[v] = dis[v]*sum(g[src]) + deg*EPS ----------------

template <int WRITEG>
__global__ void __launch_bounds__(128) prop(const half_t* __restrict__ gin,
                                            half_t* __restrict__ hout, int hstride,
                                            half_t* __restrict__ gout,
                                            const float* __restrict__ dis,
                                            const int* __restrict__ off,
                                            const int* __restrict__ esrc, int N) {
    const int c = threadIdx.x;
    for (int v = blockIdx.x; v < N; v += gridDim.x) {
        int s = off[v], e = off[v + 1];
        float a0 = 0.f, a1 = 0.f, a2 = 0.f, a3 = 0.f;
        int i = s;
        for (; i + 4 <= e; i += 4) {
            int s0 = esrc[i], s1 = esrc[i + 1], s2 = esrc[i + 2], s3 = esrc[i + 3];
            half_t p0 = gin[(s0 << 7) + c];
            half_t p1 = gin[(s1 << 7) + c];
            half_t p2 = gin[(s2 << 7) + c];
            half_t p3 = gin[(s3 << 7) + c];
            a0 += (float)p0;
            a1 += (float)p1;
            a2 += (float)p2;
            a3 += (float)p3;
        }
        for (; i < e; ++i) a0 += (float)gin[(esrc[i] << 7) + c];
        float dv = dis[v];
        float h = dv * ((a0 + a1) + (a2 + a3)) + (float)(e - s) * EPS_MSG;
        hout[(size_t)v * hstride + c] = (half_t)h;
        if (WRITEG) gout[(v << 7) + c] = (half_t)(dv * h);
    }
}

// ---------------- f16 MFMA GEMM ----------------
// C[M,Ntot](ldc) = A[M,Ktot] @ (Bh + Bl/1024)[Ntot][ldb]^T
// epi: 1=+bias 2=relu(bn(v+bias)) 3=relu(v+bias); optional gout=fp16(dis*v)

template <int BN, int OUTF32>
__global__ __launch_bounds__(256) void gemmf16(
    int M, int Ktot, int Ntot, int ldc, int ldb,
    const half_t* __restrict__ A, const half_t* __restrict__ Bhp,
    const half_t* __restrict__ Blp, void* __restrict__ Cp,
    int epi, const float* __restrict__ bias, const float* __restrict__ bng,
    const float* __restrict__ bnb, half_t* __restrict__ gout,
    const float* __restrict__ dis) {
    constexpr int BM = 64, BK = 32, PAD = 40;  // 80B row stride: 16B-aligned, odd x16
    constexpr int WC = (BN == 128) ? 2 : 1;    // waves along N
    constexpr int WR = 4 / WC;                 // waves along M
    constexpr int WROWS = BM / WR;
    constexpr int WCOLS = BN / WC;             // 64
    constexpr int MF = WROWS / 16;
    constexpr int NF = WCOLS / 16;
    constexpr int BIT = (BN * BK) / (256 * 8);  // uint4 iters per B plane

    __shared__ half_t Ah[BM][PAD];
    __shared__ half_t Bh[BN][PAD];
    __shared__ half_t Bl[BN][PAD];

    const int tid = threadIdx.x;
    const int lane = tid & 63;
    const int w = tid >> 6;
    const int wr = w / WC, wc = w % WC;
    const int m0 = blockIdx.x * BM;
    const int n0 = blockIdx.y * BN;

    uint4 ra, rbh[BIT], rbl[BIT];

    auto stage_load = [&](int k0) {
        {
            int f = tid * 8;
            int r = f >> 5, kk = f & 31;
            int gr = m0 + r;
            ra = (gr < M) ? *reinterpret_cast<const uint4*>(&A[(size_t)gr * Ktot + k0 + kk])
                          : make_uint4(0u, 0u, 0u, 0u);
        }
#pragma unroll
        for (int it = 0; it < BIT; ++it) {
            int f = (tid + it * 256) * 8;
            int r = f >> 5, kk = f & 31;
            rbh[it] = *reinterpret_cast<const uint4*>(&Bhp[(size_t)(n0 + r) * ldb + k0 + kk]);
            rbl[it] = *reinterpret_cast<const uint4*>(&Blp[(size_t)(n0 + r) * ldb + k0 + kk]);
        }
    };
    auto stage_write = [&]() {
        {
            int f = tid * 8;
            int r = f >> 5, kk = f & 31;
            *reinterpret_cast<uint4*>(&Ah[r][kk]) = ra;
        }
#pragma unroll
        for (int it = 0; it < BIT; ++it) {
            int f = (tid + it * 256) * 8;
            int r = f >> 5, kk = f & 31;
            *reinterpret_cast<uint4*>(&Bh[r][kk]) = rbh[it];
            *reinterpret_cast<uint4*>(&Bl[r][kk]) = rbl[it];
        }
    };

    f32x4 acch[MF][NF], accl[MF][NF];
#pragma unroll
    for (int fm = 0; fm < MF; ++fm)
#pragma unroll
        for (int fn = 0; fn < NF; ++fn) {
            acch[fm][fn] = (f32x4){0.f, 0.f, 0.f, 0.f};
            accl[fm][fn] = (f32x4){0.f, 0.f, 0.f, 0.f};
        }

    stage_load(0);
    const int kiters = Ktot / BK;
    for (int ki = 0; ki < kiters; ++ki) {
        stage_write();
        __syncthreads();
        if (ki + 1 < kiters) stage_load((ki + 1) * BK);

        const int koff = (lane >> 4) * 8;
        f16x8 af[MF];
#pragma unroll
        for (int fm = 0; fm < MF; ++fm) {
            int rowb = wr * WROWS + fm * 16 + (lane & 15);
            af[fm] = *reinterpret_cast<const f16x8*>(&Ah[rowb][koff]);
        }
#pragma unroll
        for (int fn = 0; fn < NF; ++fn) {
            int colb = wc * WCOLS + fn * 16 + (lane & 15);
            f16x8 bh = *reinterpret_cast<const f16x8*>(&Bh[colb][koff]);
            f16x8 bl = *reinterpret_cast<const f16x8*>(&Bl[colb][koff]);
#pragma unroll
            for (int fm = 0; fm < MF; ++fm) {
                acch[fm][fn] =
                    __builtin_amdgcn_mfma_f32_16x16x32_f16(af[fm], bh, acch[fm][fn], 0, 0, 0);
                accl[fm][fn] =
                    __builtin_amdgcn_mfma_f32_16x16x32_f16(af[fm], bl, accl[fm][fn], 0, 0, 0);
            }
        }
        __syncthreads();
    }

    // C/D layout: col = lane&15, row = (lane>>4)*4 + i
#pragma unroll
    for (int fm = 0; fm < MF; ++fm) {
#pragma unroll
        for (int fn = 0; fn < NF; ++fn) {
#pragma unroll
            for (int i = 0; i < 4; ++i) {
                int gr = m0 + wr * WROWS + fm * 16 + (lane >> 4) * 4 + i;
                if (gr >= M) continue;
                int gc = n0 + wc * WCOLS + fn * 16 + (lane & 15);
                float v = acch[fm][fn][i] + accl[fm][fn][i] * LO_INV;
                if (epi == 1) {
                    v += bias[gc];
                } else if (epi == 2) {
                    v = bng[gc] * ((v + bias[gc]) * BNSCALE) + bnb[gc];
                    v = fmaxf(v, 0.f);
                } else if (epi == 3) {
                    v = fmaxf(v + bias[gc], 0.f);
                }
                if (OUTF32)
                    ((float*)Cp)[(size_t)gr * ldc + gc] = v;
                else
                    ((half_t*)Cp)[(size_t)gr * ldc + gc] = (half_t)v;
                if (gout) gout[(gr << 7) + gc] = (half_t)(dis[gr] * v);
            }
        }
    }
}

extern "C" void kernel_launch(void* const* d_in, const int* in_sizes, int n_in,
                              void* d_out, int out_size, void* d_ws, size_t ws_size,
                              hipStream_t stream) {
    const float* x     = (const float*)d_in[0];
    const int*   ei    = (const int*)d_in[1];
    const float* lins1 = (const float*)d_in[2];
    const float* bias1 = (const float*)d_in[3];
    const float* m1w1  = (const float*)d_in[4];
    const float* m1b1  = (const float*)d_in[5];
    const float* bn1g  = (const float*)d_in[6];
    const float* bn1b  = (const float*)d_in[7];
    const float* m1w2  = (const float*)d_in[8];
    const float* m1b2  = (const float*)d_in[9];
    const float* lins2 = (const float*)d_in[10];
    const float* bias2 = (const float*)d_in[11];
    const float* m2w1  = (const float*)d_in[12];
    const float* m2b1  = (const float*)d_in[13];
    const float* bn2g  = (const float*)d_in[14];
    const float* bn2b  = (const float*)d_in[15];
    const float* m2w2  = (const float*)d_in[16];
    const float* m2b2  = (const float*)d_in[17];
    float* out = (float*)d_out;

    const int N = in_sizes[0] / 128;
    const int E = in_sizes[1] / 2;
    const int* row = ei;
    const int* col = ei + E;

    char* ws = (char*)d_ws;
    size_t o = 0;
    auto alloc = [&](size_t bytes) {
        void* p = ws + o;
        o += (bytes + 255) & ~(size_t)255;
        return p;
    };
    int*    deg  = (int*)alloc((size_t)N * 4);
    int*    cur  = (int*)alloc((size_t)N * 4);
    float*  dis  = (float*)alloc((size_t)N * 4);
    int*    off  = (int*)alloc((size_t)(N + 1) * 4);
    int*    bsum = (int*)alloc(1024 * 4);
    int*    esrc = (int*)alloc((size_t)E * 4);
    half_t* gA   = (half_t*)alloc((size_t)N * 128 * 2);  // N*256B each: gB contiguous
    half_t* gB   = (half_t*)alloc((size_t)N * 128 * 2);  // => Z=[N,256] over gA..gB
    half_t* ACC  = (half_t*)alloc((size_t)N * 128 * 2);
    half_t* ACC2 = (half_t*)alloc((size_t)N * 64 * 2);
    half_t* Wc1h = (half_t*)alloc((size_t)128 * 896 * 2);
    half_t* Wc1l = (half_t*)alloc((size_t)128 * 896 * 2);
    half_t* Wc2h = (half_t*)alloc((size_t)64 * 896 * 2);
    half_t* Wc2l = (half_t*)alloc((size_t)64 * 896 * 2);
    half_t* Wm1ah = (half_t*)alloc((size_t)256 * 128 * 2);
    half_t* Wm1al = (half_t*)alloc((size_t)256 * 128 * 2);
    half_t* Wm1bh = (half_t*)alloc((size_t)128 * 256 * 2);
    half_t* Wm1bl = (half_t*)alloc((size_t)128 * 256 * 2);
    half_t* Wm2ah = (half_t*)alloc((size_t)128 * 64 * 2);
    half_t* Wm2al = (half_t*)alloc((size_t)128 * 64 * 2);
    half_t* Wm2bh = (half_t*)alloc((size_t)64 * 128 * 2);
    half_t* Wm2bl = (half_t*)alloc((size_t)64 * 128 * 2);
    half_t* H = (half_t*)alloc((size_t)N * 896 * 2);  // [N][896] hop features
    (void)ws_size;

    half_t* Z  = gA;  // [N,256] spans gA..gB (MLP1 intermediate)
    half_t* Z2 = gA;  // [N,128] (MLP2 intermediate)

    const int TPB = 256;
    const int nb = (N + 1023) / 1024;
    zero_i32<<<(N + TPB - 1) / TPB, TPB, 0, stream>>>(deg, N);
    zero_i32<<<(N + TPB - 1) / TPB, TPB, 0, stream>>>(cur, N);
    count_deg<<<(E + TPB - 1) / TPB, TPB, 0, stream>>>(col, deg, E);
    compute_dis<<<(N + TPB - 1) / TPB, TPB, 0, stream>>>(deg, dis, N);
    scan_blk<<<nb, 1024, 0, stream>>>(deg, off, bsum, N);
    scan_top<<<1, 64, 0, stream>>>(bsum, nb);
    scan_add<<<nb, 1024, 0, stream>>>(off, bsum, N);
    fill_edges<<<(E + TPB - 1) / TPB, TPB, 0, stream>>>(row, col, off, cur, esrc, E);

    conv_wt2<<<(7 * 128 * 128 + TPB - 1) / TPB, TPB, 0, stream>>>(lins1, Wc1h, Wc1l, 7, 128, 128);
    conv_wt2<<<(7 * 128 * 64 + TPB - 1) / TPB, TPB, 0, stream>>>(lins2, Wc2h, Wc2l, 7, 128, 64);
    conv_wt2<<<(128 * 256 + TPB - 1) / TPB, TPB, 0, stream>>>(m1w1, Wm1ah, Wm1al, 1, 128, 256);
    conv_wt2<<<(256 * 128 + TPB - 1) / TPB, TPB, 0, stream>>>(m1w2, Wm1bh, Wm1bl, 1, 256, 128);
    conv_wt2<<<(64 * 128 + TPB - 1) / TPB, TPB, 0, stream>>>(m2w1, Wm2ah, Wm2al, 1, 64, 128);
    conv_wt2<<<(128 * 64 + TPB - 1) / TPB, TPB, 0, stream>>>(m2w2, Wm2bh, Wm2bl, 1, 128, 64);

    conv_xg<<<(N * 128 + TPB - 1) / TPB, TPB, 0, stream>>>(x, H, 896, gA, dis, N * 128);

    const int HG = (N + 63) / 64;
    const int PGRID = 8192;
    auto g128 = [&](const half_t* A, int Ktot, const half_t* Bh, const half_t* Bl, int ldb,
                    void* C, int ldc, int Ntot, int epi, const float* b, const float* g,
                    const float* bb, half_t* gout) {
        dim3 grid(HG, Ntot / 128);
        gemmf16<128, 0><<<grid, 256, 0, stream>>>(N, Ktot, Ntot, ldc, ldb, A, Bh, Bl, C, epi, b,
                                                  g, bb, gout, dis);
    };

    // ---- Layer 1 TAGConv: hops 1..6, then one K=896 GEMM ----
    {
        half_t* gp[2] = {gA, gB};
        for (int k = 1; k <= 6; ++k) {
            const half_t* gin = gp[(k - 1) & 1];
            half_t* gout = gp[k & 1];
            if (k < 6)
                prop<1><<<PGRID, 128, 0, stream>>>(gin, H + k * 128, 896, gout, dis, off, esrc, N);
            else
                prop<0><<<PGRID, 128, 0, stream>>>(gin, H + k * 128, 896, nullptr, dis, off, esrc,
                                                   N);
        }
        g128(H, 896, Wc1h, Wc1l, 896, ACC, 128, 128, 1, bias1, nullptr, nullptr, nullptr);
    }
    // ---- MLP1 + inter-layer relu; h1 -> H slot0; g0(L2) = fp16(dis*h1) -> ACC ----
    g128(ACC, 128, Wm1ah, Wm1al, 128, Z, 256, 256, 2, m1b1, bn1g, bn1b, nullptr);
    g128(Z, 256, Wm1bh, Wm1bl, 256, H, 896, 128, 3, m1b2, nullptr, nullptr, ACC);

    // ---- Layer 2 TAGConv ----
    {
        const half_t* gin = ACC;
        half_t* gp[2] = {gA, gB};
        for (int k = 1; k <= 6; ++k) {
            half_t* gout = gp[(k - 1) & 1];
            if (k < 6)
                prop<1><<<PGRID, 128, 0, stream>>>(gin, H + k * 128, 896, gout, dis, off, esrc, N);
            else
                prop<0><<<PGRID, 128, 0, stream>>>(gin, H + k * 128, 896, nullptr, dis, off, esrc,
                                                   N);
            gin = gout;
        }
        dim3 grid(HG, 1);
        gemmf16<64, 0><<<grid, 256, 0, stream>>>(N, 896, 64, 64, 896, H, Wc2h, Wc2l, ACC2, 1,
                                                 bias2, nullptr, nullptr, nullptr, nullptr);
    }
    // ---- MLP2 ----
    g128(ACC2, 64, Wm2ah, Wm2al, 64, Z2, 128, 128, 2, m2b1, bn2g, bn2b, nullptr);
    {
        dim3 grid(HG, 1);
        gemmf16<64, 1><<<grid, 256, 0, stream>>>(N, 128, 64, 64, 128, Z2, Wm2bh, Wm2bl, out, 1,
                                                 m2b2, nullptr, nullptr, nullptr, nullptr);
    }
}